// Round 5
// baseline (225.171 us; speedup 1.0000x reference)
//
#include <hip/hip_runtime.h>
#include <stdint.h>

#define C      1024
#define NH     16
#define HS     64
#define CT     65536
#define PAST   61440   // CT - WINDOW
#define KEEP   12288   // MIN_KV - WINDOW
#define NCOMP  192     // KEEP/64
#define NSEL   32
#define NB     8192    // selection bins
#define NBLK   256     // mega-kernel grid (1 block/CU, co-resident)

typedef unsigned long long ull;

// monotone transform: larger float => smaller u (asc u == desc value)
__device__ __forceinline__ unsigned int desc_key(float f) {
    unsigned int b = __float_as_uint(f);
    return (b >> 31) ? b : (~b & 0x7FFFFFFFu);
}
__device__ __forceinline__ float u_to_f(unsigned int u) {
    unsigned int b = (u & 0x80000000u) ? u : (0x7FFFFFFFu - u);
    return __uint_as_float(b);
}
// monotone linear bin: s descending <-> bin ascending
__device__ __forceinline__ int bin_of(float s, float hi, float scale) {
    int b = (int)((hi - s) * scale);
    return b < 0 ? 0 : (b > NB - 1 ? NB - 1 : b);
}
__device__ __forceinline__ void load_params(const unsigned* umin, const unsigned* umax,
                                            int h, float* hi, float* sc) {
    float h2 = u_to_f(umin[h]);
    float lo = u_to_f(umax[h]);
    float r = h2 - lo;
    *hi = h2;
    *sc = (r > 0.f) ? (float)(NB - 1) / r : 0.f;
}

// device-wide barrier (256 co-resident blocks; one counter per barrier site)
__device__ __forceinline__ void gsync(unsigned* cnt) {
    __syncthreads();
    if (threadIdx.x == 0) {
        __threadfence();                       // release: flush this XCD's writes
        atomicAdd(cnt, 1u);
        while (atomicAdd(cnt, 0u) < NBLK) __builtin_amdgcn_s_sleep(8);
        __threadfence();                       // acquire: invalidate stale lines
    }
    __syncthreads();
}

// ---------------- K1: q/k/v projections + all zero-inits ---------------------
__global__ void k_proj(const float* __restrict__ x, const float* __restrict__ Wr,
                       const float* __restrict__ Wk, const float* __restrict__ Wv,
                       float* __restrict__ q, float* __restrict__ kn, float* __restrict__ vn,
                       unsigned* __restrict__ hist, unsigned* __restrict__ umin,
                       unsigned* __restrict__ umax, ull* __restrict__ cs_fix,
                       unsigned* __restrict__ bar) {
    int id = blockIdx.x * 256 + threadIdx.x;
    if (id < NH * NB) hist[id] = 0;
    if (blockIdx.x == 699 && threadIdx.x < 8) bar[threadIdx.x] = 0u;
    if (blockIdx.x == 700) {
        if (threadIdx.x < 16) umin[threadIdx.x] = 0xFFFFFFFFu;
        else if (threadIdx.x < 32) umax[threadIdx.x - 16] = 0u;
    }
    if (blockIdx.x == 701 && threadIdx.x < 256) cs_fix[threadIdx.x] = 0ull;

    int w = blockIdx.x * (blockDim.x >> 6) + (threadIdx.x >> 6); // 0..3071
    int lane = threadIdx.x & 63;
    int mat = w >> 10, row = w & 1023;
    const float* W = (mat == 0) ? Wr : (mat == 1) ? Wk : Wv;
    const float4* Wrow = (const float4*)(W + (size_t)row * C);
    const float4* x4 = (const float4*)x;
    float acc = 0.f;
#pragma unroll
    for (int i = 0; i < 4; ++i) {
        float4 a = Wrow[i * 64 + lane];
        float4 b = x4[i * 64 + lane];
        acc += a.x * b.x + a.y * b.y + a.z * b.z + a.w * b.w;
    }
#pragma unroll
    for (int off = 32; off; off >>= 1) acc += __shfl_xor(acc, off);
    if (lane == 0) { (mat == 0 ? q : (mat == 1 ? kn : vn))[row] = acc; }
}

// ------- K2: scores s[h][t] = qh.k_cache[t,h]; 16 tokens/wave, 64B writes ----
__global__ void k_scores(const float* __restrict__ kc, const float* __restrict__ q,
                         float* __restrict__ s, unsigned* __restrict__ umin,
                         unsigned* __restrict__ umax) {
    __shared__ float sc_l[4][16][17];
    __shared__ float smn[4][16], smx[4][16];
    int wave = threadIdx.x >> 6, lane = threadIdx.x & 63;
    int wid = blockIdx.x * 4 + wave;           // 0..4095
    int t0 = wid * 16;
    const float4* q4 = (const float4*)q;
    float4 qv[4];
#pragma unroll
    for (int i = 0; i < 4; ++i) qv[i] = q4[i * 64 + lane];
    float mnv[4] = {3.4e38f, 3.4e38f, 3.4e38f, 3.4e38f};
    float mxv[4] = {-3.4e38f, -3.4e38f, -3.4e38f, -3.4e38f};
    for (int tt = 0; tt < 16; ++tt) {
        const float4* row = (const float4*)(kc + (size_t)(t0 + tt) * C);
        float acc[4];
#pragma unroll
        for (int i = 0; i < 4; ++i) {
            float4 a = row[i * 64 + lane];
            acc[i] = a.x * qv[i].x + a.y * qv[i].y + a.z * qv[i].z + a.w * qv[i].w;
        }
#pragma unroll
        for (int off = 8; off; off >>= 1) {
#pragma unroll
            for (int i = 0; i < 4; ++i) acc[i] += __shfl_xor(acc[i], off);
        }
        if ((lane & 15) == 0) {
            int g = lane >> 4;
#pragma unroll
            for (int i = 0; i < 4; ++i) {
                sc_l[wave][4 * i + g][tt] = acc[i];
                mnv[i] = fminf(mnv[i], acc[i]);
                mxv[i] = fmaxf(mxv[i], acc[i]);
            }
        }
    }
    __syncthreads();
    // contiguous 64B-per-head writes (16 consecutive tokens per 16-lane group)
    int tt2 = lane & 15;
#pragma unroll
    for (int r = 0; r < 4; ++r) {
        int h = r * 4 + (lane >> 4);
        s[(size_t)h * CT + t0 + tt2] = sc_l[wave][h][tt2];
    }
    if (blockIdx.x < 960) {                     // all 4 waves fully in PAST region
        if ((lane & 15) == 0) {
            int g = lane >> 4;
#pragma unroll
            for (int i = 0; i < 4; ++i) { smn[wave][4 * i + g] = mnv[i]; smx[wave][4 * i + g] = mxv[i]; }
        }
        __syncthreads();
        if (threadIdx.x < 16) {
            int h = threadIdx.x;
            float mn = smn[0][h], mx = smx[0][h];
            for (int w2 = 1; w2 < 4; ++w2) {
                mn = fminf(mn, smn[w2][h]);
                mx = fmaxf(mx, smx[w2][h]);
            }
            atomicMin(&umin[h], desc_key(mx));
            atomicMax(&umax[h], desc_key(mn));
        }
    }
}

// -------- K3 (mega): hist -> scan||winsum -> scatter -> rank -> attn -> out --
__global__ __launch_bounds__(1024, 4) void k_mega(
        const float* __restrict__ s, const float* __restrict__ vc,
        const unsigned* __restrict__ umin, const unsigned* __restrict__ umax,
        unsigned* __restrict__ base, unsigned* __restrict__ Tarr,
        ull* __restrict__ G, unsigned short* __restrict__ stok,
        ull* __restrict__ cs_fix, float* __restrict__ part,
        const float* __restrict__ q, const float* __restrict__ kn,
        const float* __restrict__ vn, const float* __restrict__ Wo,
        float* __restrict__ out, unsigned* __restrict__ bar) {
    const int bid = blockIdx.x, tid = threadIdx.x;
    const int lane = tid & 63, wave = tid >> 6;
    __shared__ __align__(16) char smem[40960];

    // ---- Phase C: histogram (16 blocks per head, LDS hist -> global atomics)
    {
        unsigned* lh = (unsigned*)smem;
        int h = bid >> 4, seg = bid & 15;
        for (int i = tid; i < NB; i += 1024) lh[i] = 0;
        __syncthreads();
        float hi, sc; load_params(umin, umax, h, &hi, &sc);
        const float* sh = s + (size_t)h * CT + seg * 3840;
        for (int i = tid; i < 3840; i += 1024)
            atomicAdd(&lh[bin_of(sh[i], hi, sc)], 1u);
        __syncthreads();
        unsigned* gh = base + h * NB;
        for (int i = tid; i < NB; i += 1024) {
            unsigned c = lh[i];
            if (c) atomicAdd(&gh[i], c);
        }
    }
    gsync(bar + 0);

    // ---- Phase D: scan+threshold (blocks 0..15) || window-chunk sums (rest)
    if (bid < 16) {
        unsigned* wsum = (unsigned*)smem;
        int h = bid;
        unsigned* B = base + h * NB;
        unsigned cnt[8];
        unsigned loc = 0;
        int b0 = tid * 8;
#pragma unroll
        for (int k = 0; k < 8; ++k) { cnt[k] = B[b0 + k]; loc += cnt[k]; }
        unsigned run = loc;
#pragma unroll
        for (int off = 1; off < 64; off <<= 1) {
            unsigned n = __shfl_up(run, off);
            if (lane >= off) run += n;
        }
        if (lane == 63) wsum[wave] = run;
        __syncthreads();
        if (wave == 0 && lane < 16) {
            unsigned v = wsum[lane];
#pragma unroll
            for (int off = 1; off < 16; off <<= 1) {
                unsigned n = __shfl_up(v, off);
                if (lane >= off) v += n;
            }
            wsum[lane] = v;
        }
        __syncthreads();
        unsigned r = run - loc + (wave ? wsum[wave - 1] : 0u);
#pragma unroll
        for (int k = 0; k < 8; ++k) {
            unsigned c = cnt[k];
            B[b0 + k] = r;
            unsigned inc = r + c;
            if (r < KEEP && inc >= KEEP) Tarr[h] = (unsigned)(b0 + k);
            r = inc;
        }
    } else {
        int gw = (bid - 16) * 16 + wave;        // 0..3839
        if (gw < NH * 64) {
            int h = gw >> 6, c2 = gw & 63;
            float v = s[(size_t)h * CT + PAST + c2 * 64 + lane];
            long long f = llrintf(v * 16777216.f);
#pragma unroll
            for (int off = 32; off; off >>= 1) f += __shfl_xor(f, off);
            if (lane == 0) atomicAdd(&cs_fix[NCOMP + c2], (ull)f);
        }
    }
    gsync(bar + 1);

    // ---- Phase E: scatter candidates (bins <= T)
    for (int i = bid * 1024 + tid; i < NH * PAST; i += NBLK * 1024) {
        int h = i / PAST, t = i - h * PAST;
        float hi, sc; load_params(umin, umax, h, &hi, &sc);
        float v = s[(size_t)h * CT + t];
        int b = bin_of(v, hi, sc);
        if ((unsigned)b <= Tarr[h]) {
            unsigned pos = atomicAdd(&base[h * NB + b], 1u);
            G[(size_t)h * 65536 + pos] = ((ull)desc_key(v) << 16) | (unsigned)t;
        }
    }
    gsync(bar + 2);

    // ---- Phase F: exact rank within bin; emit stok + compacted chunk sums
    {
        ull* csl = (ull*)smem;
        if (tid < NCOMP) csl[tid] = 0ull;
        __syncthreads();
        int h = bid >> 4, seg = bid & 15;
        float hi, sc; load_params(umin, umax, h, &hi, &sc);
        unsigned T = Tarr[h];
        unsigned ncand = base[h * NB + T];
        const ull* Gh = G + (size_t)h * 65536;
        for (unsigned p = seg * 1024 + tid; p < ncand; p += 16384) {
            ull pk = Gh[p];
            unsigned u = (unsigned)(pk >> 16);
            float v = u_to_f(u);
            int b = bin_of(v, hi, sc);
            unsigned start = b ? base[h * NB + b - 1] : 0u;
            unsigned end = base[h * NB + b];
            unsigned rank = start;
            for (unsigned j = start; j < end; ++j) rank += (Gh[j] < pk) ? 1u : 0u;
            if (rank < KEEP) {
                stok[h * KEEP + rank] = (unsigned short)(pk & 0xFFFFull);
                long long f = llrintf(v * 16777216.f);
                atomicAdd(&csl[rank >> 6], (ull)f);
            }
        }
        __syncthreads();
        if (tid < NCOMP) {
            ull c = csl[tid];
            if (c) atomicAdd(&cs_fix[tid], c);
        }
    }
    gsync(bar + 3);

    // ---- Phase H: top-32 (redundant per block) + partial softmax+PV (2 pairs)
    {
        ull* key = (ull*)smem;                       // 2048 B
        unsigned* sel_l = (unsigned*)(smem + 2048);  // 128 B
        float* scm = (float*)(smem + 2176);          // 512 B (2x64)
        float* exb = (float*)(smem + 2688);          // 512 B (2x64)
        float* vbuf = (float*)(smem + 3200);         // 2 x 64 x 68 floats
        if (tid < 256) {
            long long v = (long long)cs_fix[tid];
            ull bb = (ull)(v + (1ll << 45));
            key[tid] = (((1ull << 46) - bb) << 8) | (unsigned)tid;
        }
        __syncthreads();
        for (unsigned k = 2; k <= 256; k <<= 1) {
            for (unsigned j = k >> 1; j > 0; j >>= 1) {
                if (tid < 256) {
                    unsigned ixj = tid ^ j;
                    if (ixj > (unsigned)tid) {
                        ull a = key[tid], b = key[ixj];
                        bool up = ((tid & k) == 0);
                        if (up ? (a > b) : (a < b)) { key[tid] = b; key[ixj] = a; }
                    }
                }
                __syncthreads();
            }
        }
        if (tid < NSEL) sel_l[tid] = (unsigned)(key[tid] & 0xFFull);
        __syncthreads();

        int su = tid >> 9, sid = tid & 511;
        int p = bid * 2 + su;                    // 0..511
        int h = p >> 5, ci = p & 31;
        int c = (int)sel_l[ci];
        int g = sid >> 3, q8 = sid & 7;
        int t = (c < NCOMP) ? (int)stok[h * KEEP + c * 64 + g]
                            : (PAST + (c - NCOMP) * 64 + g);
        if (q8 == 0) scm[su * 64 + g] = s[(size_t)h * CT + t] * 0.125f;
        __syncthreads();
        float m = -1e30f;
        for (int j = 0; j < 64; ++j) m = fmaxf(m, scm[su * 64 + j]);
        float e = expf(scm[su * 64 + g] - m);
        if (q8 == 0) exb[su * 64 + g] = e;
        const float4* vrow = (const float4*)(vc + (size_t)t * C + h * HS);
        float4 v0 = vrow[q8 * 2], v1 = vrow[q8 * 2 + 1];
        float* vb = vbuf + su * 4352 + g * 68 + q8 * 8;
        vb[0] = e * v0.x; vb[1] = e * v0.y; vb[2] = e * v0.z; vb[3] = e * v0.w;
        vb[4] = e * v1.x; vb[5] = e * v1.y; vb[6] = e * v1.z; vb[7] = e * v1.w;
        __syncthreads();
        if (sid < 64) {
            float acc = 0.f;
            for (int g2 = 0; g2 < 64; ++g2) acc += vbuf[su * 4352 + g2 * 68 + sid];
            float* P = part + (size_t)(h * 32 + ci) * 68;
            P[2 + sid] = acc;
            if (sid == 0) {
                float es = 0.f;
                for (int g2 = 0; g2 < 64; ++g2) es += exb[su * 64 + g2];
                P[0] = m;
                P[1] = es;
            }
        }
    }
    gsync(bar + 4);
    if (bid >= 64) return;

    // ---- Phase J: combine partials -> y (LDS, redundant) -> out = y @ Wo.T
    {
        float* yl = (float*)smem;                 // 4 KB
        float* qdl = (float*)(smem + 4096);       // 64 B
        if (tid < 16) {
            float qd = 0.f;
            for (int l = 0; l < 64; ++l) qd += q[tid * 64 + l] * kn[tid * 64 + l];
            qdl[tid] = qd;
        }
        __syncthreads();
        {
            int h = tid >> 6, ln = tid & 63;
            float a_new = qdl[h] * 0.125f;
            const float* P0 = part + (size_t)h * 32 * 68;
            float m = a_new;
            for (int ci = 0; ci < 32; ++ci) m = fmaxf(m, P0[ci * 68]);
            float den = expf(a_new - m);
            float acc = den * vn[h * HS + ln];
            for (int ci = 0; ci < 32; ++ci) {
                float w = expf(P0[ci * 68] - m);
                den += w * P0[ci * 68 + 1];
                acc += w * P0[ci * 68 + 2 + ln];
            }
            yl[tid] = acc / den;
        }
        __syncthreads();
        int r = bid * 16 + wave;                  // 0..1023
        const float4* Wrow = (const float4*)(Wo + (size_t)r * C);
        const float4* y4 = (const float4*)yl;
        float acc = 0.f;
#pragma unroll
        for (int i = 0; i < 4; ++i) {
            float4 a = Wrow[i * 64 + lane];
            float4 b = y4[i * 64 + lane];
            acc += a.x * b.x + a.y * b.y + a.z * b.z + a.w * b.w;
        }
#pragma unroll
        for (int off = 32; off; off >>= 1) acc += __shfl_xor(acc, off);
        if (lane == 0) out[r] = acc;
    }
}

extern "C" void kernel_launch(void* const* d_in, const int* in_sizes, int n_in,
                              void* d_out, int out_size, void* d_ws, size_t ws_size,
                              hipStream_t stream) {
    const float* x  = (const float*)d_in[0];
    const float* kc = (const float*)d_in[1];
    const float* vc = (const float*)d_in[2];
    const float* Wr = (const float*)d_in[3];
    const float* Wk = (const float*)d_in[4];
    const float* Wv = (const float*)d_in[5];
    const float* Wo = (const float*)d_in[6];
    float* out = (float*)d_out;
    char* ws = (char*)d_ws;

    float* q    = (float*)(ws + 0);
    float* kn   = (float*)(ws + 8192);
    float* vn   = (float*)(ws + 16384);
    ull* cs_fix = (ull*)(ws + 32768);                         // 2 KiB
    float* part = (float*)(ws + 49152);                       // 139264 B
    unsigned short* stok = (unsigned short*)(ws + 196608);    // 393216 B
    unsigned* umin = (unsigned*)(ws + 602112);
    unsigned* umax = (unsigned*)(ws + 602176);
    unsigned* Tarr = (unsigned*)(ws + 602240);
    unsigned* bar  = (unsigned*)(ws + 602368);                // 8 barrier counters
    unsigned* base = (unsigned*)(ws + 655360);                // 16*8192*4 = 512 KiB
    float* s = (float*)(ws + 2097152);                        // 4 MiB
    ull* G = (ull*)(ws + 6291456);                            // 8 MiB

    k_proj<<<768, 256, 0, stream>>>(x, Wr, Wk, Wv, q, kn, vn, base, umin, umax, cs_fix, bar);
    k_scores<<<1024, 256, 0, stream>>>(kc, q, s, umin, umax);
    k_mega<<<NBLK, 1024, 0, stream>>>(s, vc, umin, umax, base, Tarr, G, stok, cs_fix,
                                      part, q, kn, vn, Wo, out, bar);
}